// Round 7
// baseline (71.465 us; speedup 1.0000x reference)
//
#include <hip/hip_runtime.h>
#include <math.h>

// ContactModel R7: two threads per batch (one per foot), R1 numerics.
// Thread t: batch b = t>>1, foot f = t&1. Foot 0 = spheres 0..5 (bodies 4,5),
// foot 1 = spheres 6..11 (bodies 9,10); both feet have 4 spheres on the first
// body and 2 on the second. Each thread computes its 6 spheres' pos/vel/force
// plus its foot-group outputs; the all-group is recombined across the lane
// pair via __shfl_xor(1) using torque = Sum cross(pos,f_m) - cop x Sum f_m.
// Halves per-thread registers/loads/tanh-chains, doubles wave count
// (2B threads = 8192 waves = 32/CU at 8 waves/SIMD) for latency hiding.

__device__ __constant__ float c_local[12][3] = {
    {0.00190115788407966f, -0.01f, -0.00382630379623308f},
    {0.148386399942063f,   -0.01f, -0.028713422052654f},
    {0.133001170607051f,   -0.01f,  0.0516362473449566f},
    {0.0662346661991635f,  -0.01f,  0.0263641606741698f},
    {0.06f,                -0.01f, -0.0187603084619177f},
    {0.045f,               -0.01f,  0.0618569567549652f},
    {0.00190115788407966f, -0.01f,  0.00382630379623308f},
    {0.148386399942063f,   -0.01f,  0.028713422052654f},
    {0.133001170607051f,   -0.01f, -0.0516362473449566f},
    {0.0662346661991635f,  -0.01f, -0.0263641606741698f},
    {0.06f,                -0.01f,  0.0187603084619177f},
    {0.045f,               -0.01f, -0.0618569567549652f}};

__global__ __launch_bounds__(256)
void contact_kernel(const float* __restrict__ joints,
                    const float* __restrict__ jori,
                    float* __restrict__ out, const int B)
{
    const long t = (long)blockIdx.x * blockDim.x + threadIdx.x;
    if (t >= 2L * B) return;              // 2B even => shfl partners die together
    const int b = (int)(t >> 1);
    const int f = (int)(t & 1);

    float px[6], py[6], pz[6];
    float fx[6], fy[6], fz[6];            // velocity first, then force in-place

    // ---- positions + velocity for this foot's 6 spheres ----
    {
        const int body0 = f ? 9 : 4;
        const int bodies[2] = {body0, body0 + 1};
        const int sbeg[2]   = {0, 4};
        const int scnt[2]   = {4, 2};
        const int bp = (b > 0) ? (b - 1) : b;   // bp==b => vel exactly 0 (ref)
        const float* jr  = joints + (size_t)b  * 72;
        const float* jrp = joints + (size_t)bp * 72;
        const float* mr  = jori   + (size_t)b  * 216;
        const float* mrp = jori   + (size_t)bp * 216;

        #pragma unroll
        for (int bi = 0; bi < 2; ++bi) {
            const int body = bodies[bi];
            const float jx = jr[body*3+0], jy = jr[body*3+1], jz = jr[body*3+2];
            const float* m = mr + body*9;
            const float m00=m[0],m01=m[1],m02=m[2];
            const float m10=m[3],m11=m[4],m12=m[5];
            const float m20=m[6],m21=m[7],m22=m[8];
            const float kx = jrp[body*3+0], ky = jrp[body*3+1], kz = jrp[body*3+2];
            const float* nn = mrp + body*9;
            const float n00=nn[0],n01=nn[1],n02=nn[2];
            const float n10=nn[3],n11=nn[4],n12=nn[5];
            const float n20=nn[6],n21=nn[7],n22=nn[8];
            #pragma unroll
            for (int si = 0; si < 4; ++si) {
                if (si < scnt[bi]) {
                    const int s  = sbeg[bi] + si;        // local sphere 0..5
                    const int gs = f*6 + s;              // global sphere index
                    const float lx = c_local[gs][0];
                    const float ly = c_local[gs][1];
                    const float lz = c_local[gs][2];
                    const float ax = jx + m00*lx + m01*ly + m02*lz;
                    const float ay = jy + m10*lx + m11*ly + m12*lz;
                    const float az = jz + m20*lx + m21*ly + m22*lz;
                    const float bx = kx + n00*lx + n01*ly + n02*lz;
                    const float by = ky + n10*lx + n11*ly + n12*lz;
                    const float bz = kz + n20*lx + n21*ly + n22*lz;
                    px[s] = ax; py[s] = ay; pz[s] = az;
                    fx[s] = (ax - bx) * 20.0f;   // 1/DT = 20
                    fy[s] = (ay - by) * 20.0f;
                    fz[s] = (az - bz) * 20.0f;
                }
            }
        }
    }

    // ---- contact forces (R1 numerics, in-place over velocity) ----
    const float KF  = 1077.21734501594f;                 // 0.5 * 100000**(2/3)
    const float CFH = (4.0f/3.0f) * KF * sqrtf(0.032f * KF);
    #pragma unroll
    for (int s = 0; s < 6; ++s) {
        const float vx = fx[s], vy = fy[s], vz = fz[s];
        const float ind     = -py[s];                    // GROUND_HEIGHT = 0
        const float ind_vel = -vy;
        const float q   = ind*ind + 1e-5f;
        const float fH  = CFH * sqrtf(q * sqrtf(q));     // q^0.75
        const float fHd = fH * (1.0f + 0.3f * ind_vel);  // 1.5*DISSIPATION = 0.3
        const float t1 = (0.5f*tanhf(50.0f*(ind_vel + 3.3333333333333335f)) + 0.5f) + 1e-16f;
        const float t2 = (0.5f*tanhf(300.0f*ind) + 0.5f) + 1e-16f;
        const float fn = t1 * t2 * fHd;
        const float vslip = sqrtf(vx*vx + vz*vz + 1e-5f);
        const float vrel  = vslip * 5.0f;                // / TRANSITION_VELOCITY
        // STATIC==DYNAMIC==0.8 -> 2*(S-D)/(1+vrel^2) term is exactly 0
        const float mu  = fminf(vrel, 1.0f) * 0.8f + 0.5f * vslip;
        const float ffr = fn * mu;
        const float sc  = ffr / (vslip + 1e-5f);
        fx[s] = -sc * vx;
        fy[s] = fn;
        fz[s] = -sc * vz;
    }

    // ---- per-foot partial sums ----
    float SFx=0.f,SFy=0.f,SFz=0.f;          // all-force sum (unmasked)
    float SMx=0.f,SMy=0.f,SMz=0.f;          // masked force sum
    float T0x=0.f,T0y=0.f,T0z=0.f;          // Sum cross(pos, f_masked)
    float tw=0.f, sx=0.f, sz=0.f;           // cop weights
    #pragma unroll
    for (int s = 0; s < 6; ++s) {
        SFx += fx[s]; SFy += fy[s]; SFz += fz[s];
        if (fy[s] > 0.f) {
            tw += fy[s]; sx += px[s]*fy[s]; sz += pz[s]*fy[s];
            SMx += fx[s]; SMy += fy[s]; SMz += fz[s];
            T0x += py[s]*fz[s] - pz[s]*fy[s];
            T0y += pz[s]*fx[s] - px[s]*fz[s];
            T0z += px[s]*fy[s] - py[s]*fx[s];
        }
    }

    // ---- foot group (direct, reference-shaped) ----
    const bool  hasf = tw > 0.f;
    const float cxf  = hasf ? sx / tw : 0.f;
    const float czf  = hasf ? sz / tw : 0.f;
    float Txf=0.f, Tyf=0.f, Tzf=0.f;
    #pragma unroll
    for (int s = 0; s < 6; ++s) {
        if (fy[s] > 0.f) {
            const float rx = px[s]-cxf, ry = py[s], rz = pz[s]-czf;  // cy==0
            Txf += ry*fz[s] - rz*fy[s];
            Tyf += rz*fx[s] - rx*fz[s];
            Tzf += rx*fy[s] - ry*fx[s];
        }
    }

    // ---- all group via lane-pair exchange ----
    const float otw  = __shfl_xor(tw, 1),  osx  = __shfl_xor(sx, 1),  osz  = __shfl_xor(sz, 1);
    const float oFx  = __shfl_xor(SFx, 1), oFy  = __shfl_xor(SFy, 1), oFz  = __shfl_xor(SFz, 1);
    const float oMx  = __shfl_xor(SMx, 1), oMy  = __shfl_xor(SMy, 1), oMz  = __shfl_xor(SMz, 1);
    const float oT0x = __shfl_xor(T0x, 1), oT0y = __shfl_xor(T0y, 1), oT0z = __shfl_xor(T0z, 1);
    const float twa  = tw + otw;
    const bool  hasa = twa > 0.f;
    const float cxa  = hasa ? (sx + osx) / twa : 0.f;
    const float cza  = hasa ? (sz + osz) / twa : 0.f;
    const float aMx = SMx + oMx, aMy = SMy + oMy, aMz = SMz + oMz;
    // T_all = Sum T0 - cop x Sum M, cop=(cxa,0,cza)
    const float Txa = (T0x + oT0x) + cza*aMy;
    const float Tya = (T0y + oT0y) - cza*aMx + cxa*aMz;
    const float Tza = (T0z + oT0z) - cxa*aMy;

    // ---- stores ----
    // out layout (floats): force 0 | torque 3B | cop 6B | sf 9B | pos 45B
    //   | f_r 81B | f_l 84B | t_r 87B | t_l 90B | c_r 93B | c_l 96B
    const size_t sB = (size_t)B;
    const size_t t3 = (size_t)b * 3;
    float* o;
    o = out + sB*(81 + f*3);  o[t3]=SFx; o[t3+1]=SFy; o[t3+2]=SFz;
    o = out + sB*(87 + f*3);  o[t3]=Txf; o[t3+1]=Tyf; o[t3+2]=Tzf;
    o = out + sB*(93 + f*3);  o[t3]=cxf; o[t3+1]=0.f; o[t3+2]=czf;
    if (f == 0) {
        o = out;          o[t3]=SFx+oFx; o[t3+1]=SFy+oFy; o[t3+2]=SFz+oFz;
        o = out + sB*3;   o[t3]=Txa;     o[t3+1]=Tya;     o[t3+2]=Tza;
        o = out + sB*6;   o[t3]=cxa;     o[t3+1]=0.f;     o[t3+2]=cza;
    }

    // sphere_forces / pos: 18 contiguous floats at base + b*36 + f*18.
    float* osf = out + sB*9  + (size_t)b*36 + f*18;
    float* opp = out + sB*45 + (size_t)b*36 + f*18;
    if ((B & 3) == 0) {
        // region bases 16B-aligned; b*144 16B-aligned; f*72 -> f=0 aligned 16,
        // f=1 aligned 8 with +8 restoring 16-alignment.
        float bufF[18], bufP[18];
        #pragma unroll
        for (int s = 0; s < 6; ++s) {
            bufF[s*3+0]=fx[s]; bufF[s*3+1]=fy[s]; bufF[s*3+2]=fz[s];
            bufP[s*3+0]=px[s]; bufP[s*3+1]=py[s]; bufP[s*3+2]=pz[s];
        }
        if (f == 0) {
            #pragma unroll
            for (int i = 0; i < 4; ++i) {
                reinterpret_cast<float4*>(osf)[i] = reinterpret_cast<const float4*>(bufF)[i];
                reinterpret_cast<float4*>(opp)[i] = reinterpret_cast<const float4*>(bufP)[i];
            }
            reinterpret_cast<float2*>(osf)[8] = make_float2(bufF[16], bufF[17]);
            reinterpret_cast<float2*>(opp)[8] = make_float2(bufP[16], bufP[17]);
        } else {
            reinterpret_cast<float2*>(osf)[0] = make_float2(bufF[0], bufF[1]);
            reinterpret_cast<float2*>(opp)[0] = make_float2(bufP[0], bufP[1]);
            #pragma unroll
            for (int i = 0; i < 4; ++i) {
                reinterpret_cast<float4*>(osf + 2)[i] =
                    make_float4(bufF[2+i*4], bufF[3+i*4], bufF[4+i*4], bufF[5+i*4]);
                reinterpret_cast<float4*>(opp + 2)[i] =
                    make_float4(bufP[2+i*4], bufP[3+i*4], bufP[4+i*4], bufP[5+i*4]);
            }
        }
    } else {
        #pragma unroll
        for (int s = 0; s < 6; ++s) {
            osf[s*3+0]=fx[s]; osf[s*3+1]=fy[s]; osf[s*3+2]=fz[s];
            opp[s*3+0]=px[s]; opp[s*3+1]=py[s]; opp[s*3+2]=pz[s];
        }
    }
}

extern "C" void kernel_launch(void* const* d_in, const int* in_sizes, int n_in,
                              void* d_out, int out_size, void* d_ws, size_t ws_size,
                              hipStream_t stream) {
    const float* joints = (const float*)d_in[0];
    const float* jori   = (const float*)d_in[1];
    float* out = (float*)d_out;
    const int B = in_sizes[0] / 72;            // joints is (B, 24, 3)
    const long threads = 2L * B;
    const int  block = 256;
    const int  grid  = (int)((threads + block - 1) / block);
    contact_kernel<<<grid, block, 0, stream>>>(joints, jori, out, B);
}